// Round 1
// baseline (357.160 us; speedup 1.0000x reference)
//
#include <hip/hip_runtime.h>
#include <hip/hip_bf16.h>

#define D_S 128

// ---------------------------------------------------------------------------
// Kernel 1: per-node precompute
//   AB[n][k]     = dot(W1[k, 0:128],   s[n]) + b1[k]   for k in [0,128)
//   AB[n][128+k] = dot(W1[k, 128:256], s[n])           for k in [0,128)
// 1 thread = 1 node; blockIdx.y splits the 256 outputs into 8 chunks of 32.
// ---------------------------------------------------------------------------
__global__ __launch_bounds__(64) void precompute_ab(
    const float* __restrict__ s, const float* __restrict__ W1,
    const float* __restrict__ b1, float* __restrict__ AB, int n_nodes) {
  int n = blockIdx.x * 64 + threadIdx.x;
  bool valid = (n < n_nodes);
  int nc = valid ? n : 0;

  // Load this node's 128 features into registers (32 x float4).
  float4 sr[32];
  const float4* sp = (const float4*)(s + (size_t)nc * D_S);
#pragma unroll
  for (int i = 0; i < 32; ++i) sr[i] = sp[i];

  int k0 = blockIdx.y * 32;  // chunk of 32 outputs in [0,256)

#pragma unroll 1
  for (int kk = 0; kk < 32; ++kk) {
    int k = k0 + kk;  // wave-uniform
    // Row of the "concatenated" weight view: A-half uses W1[k][0:128],
    // B-half uses W1[k-128][128:256].
    const float* w =
        W1 + ((k < D_S) ? (size_t)k * (2 * D_S) : (size_t)(k - D_S) * (2 * D_S) + D_S);
    float a0 = 0.f, a1 = 0.f, a2 = 0.f, a3 = 0.f;  // 4 accs: break dep chain
#pragma unroll
    for (int i = 0; i < 32; ++i) {
      a0 += sr[i].x * w[4 * i + 0];
      a1 += sr[i].y * w[4 * i + 1];
      a2 += sr[i].z * w[4 * i + 2];
      a3 += sr[i].w * w[4 * i + 3];
    }
    float acc = (a0 + a1) + (a2 + a3);
    if (k < D_S) acc += b1[k];  // fold bias into the A half
    if (valid) AB[(size_t)n * 256 + k] = acc;
  }
}

// ---------------------------------------------------------------------------
// Kernel 2: per-edge. One wave (64 lanes) per edge.
//   out[e] = sum_k W2[k] * silu(AB[row][k] + AB[col][128+k]) + b2
// Lane l handles k = 2l, 2l+1 (coalesced float2 loads).
// ---------------------------------------------------------------------------
__global__ __launch_bounds__(256) void edge_kernel(
    const int* __restrict__ ei, const float* __restrict__ AB,
    const float* __restrict__ W2, const float* __restrict__ b2,
    float* __restrict__ out, int E) {
  int wave = (blockIdx.x * blockDim.x + threadIdx.x) >> 6;
  int lane = threadIdx.x & 63;
  if (wave >= E) return;
  int e = wave;

  int row = __builtin_amdgcn_readfirstlane(ei[e]);
  int col = __builtin_amdgcn_readfirstlane(ei[E + e]);

  const float2* pa = (const float2*)(AB + (size_t)row * 256) + lane;
  const float2* pb = (const float2*)(AB + (size_t)col * 256 + 128) + lane;
  float2 a = *pa;
  float2 b = *pb;
  float2 w2 = ((const float2*)W2)[lane];

  float h0 = a.x + b.x;
  float h1 = a.y + b.y;
  float s0 = h0 / (1.f + __expf(-h0));
  float s1 = h1 / (1.f + __expf(-h1));
  float p = s0 * w2.x + s1 * w2.y;

#pragma unroll
  for (int off = 32; off; off >>= 1) p += __shfl_xor(p, off, 64);

  if (lane == 0) out[e] = p + b2[0];
}

// ---------------------------------------------------------------------------
// Fallback (only if workspace is too small): direct per-edge compute.
// ---------------------------------------------------------------------------
__global__ __launch_bounds__(256) void edge_direct(
    const float* __restrict__ s, const int* __restrict__ ei,
    const float* __restrict__ W1, const float* __restrict__ b1,
    const float* __restrict__ W2, const float* __restrict__ b2,
    float* __restrict__ out, int E) {
  __shared__ float sh[256];
  __shared__ float red[128];
  int e = blockIdx.x;
  int t = threadIdx.x;
  int row = ei[e], col = ei[E + e];
  sh[t] = (t < 128) ? s[(size_t)row * D_S + t] : s[(size_t)col * D_S + (t - 128)];
  __syncthreads();
  if (t < 128) {
    float acc = b1[t];
    const float* w = W1 + (size_t)t * 256;
#pragma unroll 8
    for (int j = 0; j < 256; ++j) acc += sh[j] * w[j];
    red[t] = (acc / (1.f + __expf(-acc))) * W2[t];
  }
  __syncthreads();
  if (t < 64) {
    float x = red[t] + red[t + 64];
#pragma unroll
    for (int off = 32; off; off >>= 1) x += __shfl_xor(x, off, 64);
    if (t == 0) out[e] = x + b2[0];
  }
}

extern "C" void kernel_launch(void* const* d_in, const int* in_sizes, int n_in,
                              void* d_out, int out_size, void* d_ws, size_t ws_size,
                              hipStream_t stream) {
  const float* s  = (const float*)d_in[0];
  const int*   ei = (const int*)d_in[1];
  const float* W1 = (const float*)d_in[2];
  const float* b1 = (const float*)d_in[3];
  const float* W2 = (const float*)d_in[4];
  const float* b2 = (const float*)d_in[5];
  float* out = (float*)d_out;

  int n_nodes = in_sizes[0] / D_S;
  int E = in_sizes[1] / 2;

  size_t need = (size_t)n_nodes * 256 * sizeof(float);
  if (ws_size >= need) {
    float* AB = (float*)d_ws;
    dim3 g1((n_nodes + 63) / 64, 8);
    precompute_ab<<<g1, 64, 0, stream>>>(s, W1, b1, AB, n_nodes);
    int blocks = (E + 3) / 4;  // 4 waves per 256-thread block, 1 edge per wave
    edge_kernel<<<blocks, 256, 0, stream>>>(ei, AB, W2, b2, out, E);
  } else {
    edge_direct<<<E, 256, 0, stream>>>(s, ei, W1, b1, W2, b2, out, E);
  }
}